// Round 13
// baseline (705.657 us; speedup 1.0000x reference)
//
#include <hip/hip_runtime.h>
#include <hip/hip_bf16.h>
#include <stdint.h>

// ConditionalLoRALinear: out = x@W^T + b + mask*(2*(x@A^T)@B^T)
// M=16384, K=4096, N=4096, R=8. bf16 MFMA path.
// R13: 2-blocks/CU GEMM. BM=128, BN=256, BK=32, 512 thr (8 waves, 2Mx4N),
//      per-wave 64x64 (acc 64 regs) -> <=128 VGPR -> launch_bounds(512,4)
//      = 2 blocks/CU, 4 waves/SIMD. 3-slot LDS ring (72 KiB), counted
//      vmcnt(3), simple per-tile schedule; TLP from independent blocks
//      provides the pipe overlap that intra-block scheduling couldn't.

typedef __attribute__((ext_vector_type(8))) __bf16 bf16x8;
typedef __attribute__((ext_vector_type(4))) float f32x4;

#define M_DIM 16384
#define K_DIM 4096
#define N_DIM 4096
#define BM 128
#define BN 256
#define BK 32
#define NT3 (K_DIM / BK)   // 128

// ---------------- merged W + lora_A f32 -> bf16 conversion ----------------
__global__ __launch_bounds__(256) void cvt_wa(
    const float* __restrict__ W, __hip_bfloat16* __restrict__ Wb,
    const float* __restrict__ A, __hip_bfloat16* __restrict__ Ab) {
    int b = blockIdx.x;
    if (b < 1024) {
        int i = b * 256 + threadIdx.x;
        const int n8 = N_DIM * K_DIM / 8;
        const int stride = 1024 * 256;
        for (; i < n8; i += stride) {
            const float4* p = (const float4*)(W + (size_t)i * 8);
            float4 v0 = p[0], v1 = p[1];
            bf16x8 o;
            o[0] = (__bf16)v0.x; o[1] = (__bf16)v0.y; o[2] = (__bf16)v0.z; o[3] = (__bf16)v0.w;
            o[4] = (__bf16)v1.x; o[5] = (__bf16)v1.y; o[6] = (__bf16)v1.z; o[7] = (__bf16)v1.w;
            *(bf16x8*)((__hip_bfloat16*)Wb + (size_t)i * 8) = o;
        }
    } else {
        int i = (b - 1024) * 256 + threadIdx.x;
        if (i < 8 * K_DIM / 8) {
            const float4* p = (const float4*)(A + (size_t)i * 8);
            float4 v0 = p[0], v1 = p[1];
            bf16x8 o;
            o[0] = (__bf16)v0.x; o[1] = (__bf16)v0.y; o[2] = (__bf16)v0.z; o[3] = (__bf16)v0.w;
            o[4] = (__bf16)v1.x; o[5] = (__bf16)v1.y; o[6] = (__bf16)v1.z; o[7] = (__bf16)v1.w;
            *(bf16x8*)((__hip_bfloat16*)Ab + (size_t)i * 8) = o;
        }
    }
}

// ---------------- fused: x -> Xb (bf16) AND xa[m][r] = 2*mask*dot(x[m],A[r]) ----------------
__global__ __launch_bounds__(256) void cvt_x_xa(
    const float* __restrict__ x, const int* __restrict__ ids,
    const __hip_bfloat16* __restrict__ Abf,   // [8,4096] bf16
    __hip_bfloat16* __restrict__ Xb, float* __restrict__ xa) {
    __shared__ __hip_bfloat16 As[8 * 4096];   // 64 KiB
    int tid = threadIdx.x;
    for (int i = tid; i < 8 * 4096 / 8; i += 256)
        *(bf16x8*)(As + i * 8) = *(const bf16x8*)(Abf + i * 8);
    __syncthreads();

    int wave = tid >> 6, lane = tid & 63;
#pragma unroll
    for (int rr = 0; rr < 2; rr++) {
        int row = blockIdx.x * 8 + wave * 2 + rr;
        const float* xr = x + (size_t)row * K_DIM;
        __hip_bfloat16* xo = Xb + (size_t)row * K_DIM;
        float s[8] = {0.f, 0.f, 0.f, 0.f, 0.f, 0.f, 0.f, 0.f};
#pragma unroll
        for (int j = 0; j < 8; j++) {
            int k = j * 512 + lane * 8;
            float4 v0 = *(const float4*)(xr + k);
            float4 v1 = *(const float4*)(xr + k + 4);
            bf16x8 o;
            o[0] = (__bf16)v0.x; o[1] = (__bf16)v0.y; o[2] = (__bf16)v0.z; o[3] = (__bf16)v0.w;
            o[4] = (__bf16)v1.x; o[5] = (__bf16)v1.y; o[6] = (__bf16)v1.z; o[7] = (__bf16)v1.w;
            *(bf16x8*)(xo + k) = o;
#pragma unroll
            for (int r = 0; r < 8; r++) {
                bf16x8 av = *(const bf16x8*)(As + r * 4096 + k);
                s[r] += v0.x * (float)av[0] + v0.y * (float)av[1] + v0.z * (float)av[2] + v0.w * (float)av[3]
                      + v1.x * (float)av[4] + v1.y * (float)av[5] + v1.z * (float)av[6] + v1.w * (float)av[7];
            }
        }
#pragma unroll
        for (int r = 0; r < 8; r++) {
            float v = s[r];
            for (int off = 32; off; off >>= 1) v += __shfl_down(v, off);
            s[r] = v;
        }
        if (lane == 0) {
            float gate = (ids[row] == 7) ? 2.0f : 0.0f;
#pragma unroll
            for (int r = 0; r < 8; r++) xa[(size_t)row * 8 + r] = s[r] * gate;
        }
    }
}

// ---------------- main GEMM ----------------
__device__ __forceinline__ void gload_lds16(const void* g, void* l) {
    __builtin_amdgcn_global_load_lds(
        (const __attribute__((address_space(1))) unsigned int*)g,
        (__attribute__((address_space(3))) unsigned int*)l, 16, 0, 0);
}

#define LGKMW(n) asm volatile("s_waitcnt lgkmcnt(" #n ")" ::: "memory")
#define VMCW(n)  asm volatile("s_waitcnt vmcnt(" #n ")" ::: "memory")
#define SB0()    __builtin_amdgcn_sched_barrier(0)
#define BAR()    __builtin_amdgcn_s_barrier()
#define PRIO(p)  __builtin_amdgcn_s_setprio(p)

// LDS: 3-slot ring, slot = 24 KiB: A [128 rows][64 B] at +0 (8 KiB),
// B [256 rows][64 B] at +8 KiB (16 KiB). Row = 4 chunks of 16 B; chunk c
// stored at position p = c ^ ((row>>1)&3) (2-way residual bank alias = free).
// Staging: linear LDS dest (wave-chunk base + lane*16), inverse-swizzled
// global source (rule #21). Fragment read: row .. + l15, chunk lhi at
// p = lhi ^ ((l15>>1)&3).
__global__ __launch_bounds__(512, 4) void gemm_bias_lora(
    const __hip_bfloat16* __restrict__ Xb,   // [M, K]
    const __hip_bfloat16* __restrict__ Wb,   // [N, K]
    const float* __restrict__ bias,          // [N]
    const float* __restrict__ xa,            // [M, 8] pre-scaled & gated
    const float* __restrict__ loraB,         // [N, 8]
    float* __restrict__ out) {
    __shared__ char smem[73728];             // 72 KiB (2 blocks/CU -> 144)

    int tid = threadIdx.x;
    int bid = blockIdx.x;
    // XCD-bijective swizzle: nwg = 2048 = 8*256
    int swz = (bid & 7) * 256 + (bid >> 3);
    int n_tile = swz & 15;                   // N/BN = 16
    int m_tile = swz >> 4;                   // M/BM = 128
    int m_base = m_tile * BM, n_base = n_tile * BN;
    int wave = tid >> 6, lane = tid & 63;
    int wr = wave >> 2, wc = wave & 3;       // 2M x 4N waves, per-wave 64x64
    int l15 = lane & 15, lhi = lane >> 4;
    int cxs = ((lane & 3) ^ ((lane >> 3) & 3)) * 16;   // staging source chunk byte
    int pos = (lhi ^ ((l15 >> 1) & 3)) << 4;            // frag read position byte
    int lrow = lane >> 2;                               // staging row-within-16

    f32x4 acc[4][4] = {};

    const char* Abase = (const char*)(Xb + (size_t)m_base * K_DIM);
    const char* Bbase = (const char*)(Wb + (size_t)n_base * K_DIM);

    // stage K-tile kt into ring slot (3 gloads/thread: A x1, B x2)
    auto stage = [&](int kt, int slot) {
        char* sb = smem + slot * 24576;
        size_t kb = (size_t)kt * 64 + cxs;
        {   // A: wave w covers rows w*16 .. w*16+15
            int rl = wave * 16 + lrow;
            gload_lds16(Abase + (size_t)rl * 8192 + kb, sb + wave * 1024 + lane * 16);
        }
#pragma unroll
        for (int j = 0; j < 2; j++) {        // B: rows (w*2+j)*16 ..
            int rg = wave * 2 + j;
            int rl = rg * 16 + lrow;
            gload_lds16(Bbase + (size_t)rl * 8192 + kb, sb + 8192 + rg * 1024 + lane * 16);
        }
    };

    // prologue
    stage(0, 0);
    stage(1, 1);
    VMCW(3);          // tile0 resident; tile1's 3 in flight
    BAR();

    int s0 = 0;
    for (int t = 0; t < NT3; t++) {
        int s2 = s0 + 2; if (s2 >= 3) s2 -= 3;
        const char* aR = smem + s0 * 24576 + (wr * 64 + l15) * 64;
        const char* bR = smem + s0 * 24576 + 8192 + (wc * 64 + l15) * 64;

        bf16x8 af[4], bf[4];
#pragma unroll
        for (int mi = 0; mi < 4; mi++) af[mi] = *(const bf16x8*)(aR + mi * 1024 + pos);
#pragma unroll
        for (int ni = 0; ni < 4; ni++) bf[ni] = *(const bf16x8*)(bR + ni * 1024 + pos);
        if (t + 2 < NT3) stage(t + 2, s2);   // slot s2 last read at tile t-1 (barrier-separated)
        LGKMW(0); SB0();
        PRIO(1);
#pragma unroll
        for (int mi = 0; mi < 4; mi++)
#pragma unroll
            for (int ni = 0; ni < 4; ni++)
                acc[mi][ni] = __builtin_amdgcn_mfma_f32_16x16x32_bf16(af[mi], bf[ni], acc[mi][ni], 0, 0, 0);
        PRIO(0);
        // retire tile t+1's 3 loads (read next tile); leave tile t+2's 3
        if (t < NT3 - 2) { VMCW(3); } else { VMCW(0); }
        BAR();

        s0 = s0 + 1; if (s0 >= 3) s0 -= 3;
    }

    // epilogue: C/D layout col = lane&15, row = (lane>>4)*4 + reg
    int wrow = m_base + wr * 64;
    int wcol = n_base + wc * 64;
    float bv[4];
    float4 lb0[4], lb1[4];
#pragma unroll
    for (int ni = 0; ni < 4; ni++) {
        int n = wcol + ni * 16 + l15;
        bv[ni] = bias[n];
        lb0[ni] = *(const float4*)(loraB + (size_t)n * 8);
        lb1[ni] = *(const float4*)(loraB + (size_t)n * 8 + 4);
    }
#pragma unroll
    for (int mi = 0; mi < 4; mi++) {
#pragma unroll
        for (int r = 0; r < 4; r++) {
            int m = wrow + mi * 16 + lhi * 4 + r;
            float4 xa0 = *(const float4*)(xa + (size_t)m * 8);
            float4 xa1 = *(const float4*)(xa + (size_t)m * 8 + 4);
#pragma unroll
            for (int ni = 0; ni < 4; ni++) {
                int n = wcol + ni * 16 + l15;
                float lora = xa0.x * lb0[ni].x + xa0.y * lb0[ni].y + xa0.z * lb0[ni].z + xa0.w * lb0[ni].w
                           + xa1.x * lb1[ni].x + xa1.y * lb1[ni].y + xa1.z * lb1[ni].z + xa1.w * lb1[ni].w;
                out[(size_t)m * N_DIM + n] = acc[mi][ni][r] + bv[ni] + lora;
            }
        }
    }
}

// ---------------- fallback (ws too small): correct but slow ----------------
__global__ void fallback_kernel(const float* __restrict__ x, const int* __restrict__ ids,
                                const float* __restrict__ W, const float* __restrict__ b,
                                const float* __restrict__ A, const float* __restrict__ B8,
                                float* __restrict__ out) {
    __shared__ float xs[K_DIM];
    __shared__ float xa_s[8];
    int row = blockIdx.y;
    int t = threadIdx.x;
    const float* xr = x + (size_t)row * K_DIM;
    for (int k = t; k < K_DIM; k += 256) xs[k] = xr[k];
    __syncthreads();
    if (t < 8) {
        float s = 0.f;
        for (int k = 0; k < K_DIM; k++) s += xs[k] * A[t * K_DIM + k];
        xa_s[t] = (ids[row] == 7) ? s * 2.0f : 0.0f;
    }
    __syncthreads();
    int col = blockIdx.x * 256 + t;
    const float* wr = W + (size_t)col * K_DIM;
    float acc = 0.f;
    for (int k = 0; k < K_DIM; k++) acc += xs[k] * wr[k];
    float lora = 0.f;
#pragma unroll
    for (int rr = 0; rr < 8; rr++) lora += xa_s[rr] * B8[col * 8 + rr];
    out[(size_t)row * N_DIM + col] = acc + b[col] + lora;
}

extern "C" void kernel_launch(void* const* d_in, const int* in_sizes, int n_in,
                              void* d_out, int out_size, void* d_ws, size_t ws_size,
                              hipStream_t stream) {
    const float* x   = (const float*)d_in[0];
    const int*   ids = (const int*)d_in[1];
    const float* W   = (const float*)d_in[2];
    const float* b   = (const float*)d_in[3];
    const float* lA  = (const float*)d_in[4];
    const float* lB  = (const float*)d_in[5];
    float* out = (float*)d_out;

    size_t wb_bytes = (size_t)N_DIM * K_DIM * 2;          // 32 MiB
    size_t xb_bytes = (size_t)M_DIM * K_DIM * 2;          // 128 MiB
    size_t xa_bytes = (size_t)M_DIM * 8 * 4;              // 0.5 MiB
    size_t ab_bytes = (size_t)8 * K_DIM * 2;              // 64 KiB

    if (ws_size >= wb_bytes + xb_bytes + xa_bytes + ab_bytes) {
        __hip_bfloat16* Wb  = (__hip_bfloat16*)d_ws;
        __hip_bfloat16* Xb  = (__hip_bfloat16*)((char*)d_ws + wb_bytes);
        float*          xav = (float*)((char*)d_ws + wb_bytes + xb_bytes);
        __hip_bfloat16* Abf = (__hip_bfloat16*)((char*)d_ws + wb_bytes + xb_bytes + xa_bytes);

        cvt_wa<<<1024 + 16, 256, 0, stream>>>(W, Wb, lA, Abf);
        cvt_x_xa<<<M_DIM / 8, 256, 0, stream>>>(x, ids, Abf, Xb, xav);
        gemm_bias_lora<<<(M_DIM / BM) * (N_DIM / BN), 512, 0, stream>>>(Xb, Wb, b, xav, lB, out);
    } else {
        fallback_kernel<<<dim3(N_DIM / 256, M_DIM), 256, 0, stream>>>(x, ids, W, b, lA, lB, out);
    }
}

// Round 14
// 571.907 us; speedup vs baseline: 1.2339x; 1.2339x over previous
//
#include <hip/hip_runtime.h>
#include <hip/hip_bf16.h>
#include <stdint.h>

// ConditionalLoRALinear: out = x@W^T + b + mask*(2*(x@A^T)@B^T)
// M=16384, K=4096, N=4096, R=8. bf16 MFMA path.
// R14: verified R12 config (GEMM 475us @ MfmaUtil 56.6, prep at HBM ceiling)
//      + nontemporal C-stores (keep 256MB out-stream from evicting A/B panels
//      in L2). R13's 2-blocks/CU experiment refuted: smaller per-wave tile
//      worsens LDS-reads-per-FLOP 1.33x and doubles HBM traffic.

typedef __attribute__((ext_vector_type(8))) __bf16 bf16x8;
typedef __attribute__((ext_vector_type(4))) float f32x4;

#define M_DIM 16384
#define K_DIM 4096
#define N_DIM 4096
#define BM 256
#define BN 256
#define BK 64
#define NT2 (K_DIM / BK)   // 64

// ---------------- merged W + lora_A f32 -> bf16 conversion ----------------
__global__ __launch_bounds__(256) void cvt_wa(
    const float* __restrict__ W, __hip_bfloat16* __restrict__ Wb,
    const float* __restrict__ A, __hip_bfloat16* __restrict__ Ab) {
    int b = blockIdx.x;
    if (b < 1024) {
        int i = b * 256 + threadIdx.x;
        const int n8 = N_DIM * K_DIM / 8;
        const int stride = 1024 * 256;
        for (; i < n8; i += stride) {
            const float4* p = (const float4*)(W + (size_t)i * 8);
            float4 v0 = p[0], v1 = p[1];
            bf16x8 o;
            o[0] = (__bf16)v0.x; o[1] = (__bf16)v0.y; o[2] = (__bf16)v0.z; o[3] = (__bf16)v0.w;
            o[4] = (__bf16)v1.x; o[5] = (__bf16)v1.y; o[6] = (__bf16)v1.z; o[7] = (__bf16)v1.w;
            *(bf16x8*)((__hip_bfloat16*)Wb + (size_t)i * 8) = o;
        }
    } else {
        int i = (b - 1024) * 256 + threadIdx.x;
        if (i < 8 * K_DIM / 8) {
            const float4* p = (const float4*)(A + (size_t)i * 8);
            float4 v0 = p[0], v1 = p[1];
            bf16x8 o;
            o[0] = (__bf16)v0.x; o[1] = (__bf16)v0.y; o[2] = (__bf16)v0.z; o[3] = (__bf16)v0.w;
            o[4] = (__bf16)v1.x; o[5] = (__bf16)v1.y; o[6] = (__bf16)v1.z; o[7] = (__bf16)v1.w;
            *(bf16x8*)((__hip_bfloat16*)Ab + (size_t)i * 8) = o;
        }
    }
}

// ---------------- fused: x -> Xb (bf16) AND xa[m][r] = 2*mask*dot(x[m],A[r]) ----------------
__global__ __launch_bounds__(256) void cvt_x_xa(
    const float* __restrict__ x, const int* __restrict__ ids,
    const __hip_bfloat16* __restrict__ Abf,   // [8,4096] bf16
    __hip_bfloat16* __restrict__ Xb, float* __restrict__ xa) {
    __shared__ __hip_bfloat16 As[8 * 4096];   // 64 KiB
    int tid = threadIdx.x;
    for (int i = tid; i < 8 * 4096 / 8; i += 256)
        *(bf16x8*)(As + i * 8) = *(const bf16x8*)(Abf + i * 8);
    __syncthreads();

    int wave = tid >> 6, lane = tid & 63;
#pragma unroll
    for (int rr = 0; rr < 2; rr++) {
        int row = blockIdx.x * 8 + wave * 2 + rr;
        const float* xr = x + (size_t)row * K_DIM;
        __hip_bfloat16* xo = Xb + (size_t)row * K_DIM;
        float s[8] = {0.f, 0.f, 0.f, 0.f, 0.f, 0.f, 0.f, 0.f};
#pragma unroll
        for (int j = 0; j < 8; j++) {
            int k = j * 512 + lane * 8;
            float4 v0 = *(const float4*)(xr + k);
            float4 v1 = *(const float4*)(xr + k + 4);
            bf16x8 o;
            o[0] = (__bf16)v0.x; o[1] = (__bf16)v0.y; o[2] = (__bf16)v0.z; o[3] = (__bf16)v0.w;
            o[4] = (__bf16)v1.x; o[5] = (__bf16)v1.y; o[6] = (__bf16)v1.z; o[7] = (__bf16)v1.w;
            *(bf16x8*)(xo + k) = o;
#pragma unroll
            for (int r = 0; r < 8; r++) {
                bf16x8 av = *(const bf16x8*)(As + r * 4096 + k);
                s[r] += v0.x * (float)av[0] + v0.y * (float)av[1] + v0.z * (float)av[2] + v0.w * (float)av[3]
                      + v1.x * (float)av[4] + v1.y * (float)av[5] + v1.z * (float)av[6] + v1.w * (float)av[7];
            }
        }
#pragma unroll
        for (int r = 0; r < 8; r++) {
            float v = s[r];
            for (int off = 32; off; off >>= 1) v += __shfl_down(v, off);
            s[r] = v;
        }
        if (lane == 0) {
            float gate = (ids[row] == 7) ? 2.0f : 0.0f;
#pragma unroll
            for (int r = 0; r < 8; r++) xa[(size_t)row * 8 + r] = s[r] * gate;
        }
    }
}

// ---------------- main GEMM (VERIFIED R10/R12 kernel + nt C-stores) ----------------
__device__ __forceinline__ void gload_lds16(const void* g, void* l) {
    __builtin_amdgcn_global_load_lds(
        (const __attribute__((address_space(1))) unsigned int*)g,
        (__attribute__((address_space(3))) unsigned int*)l, 16, 0, 0);
}

#define LGKMW(n) asm volatile("s_waitcnt lgkmcnt(" #n ")" ::: "memory")
#define VMCW(n)  asm volatile("s_waitcnt vmcnt(" #n ")" ::: "memory")
#define SB0()    __builtin_amdgcn_sched_barrier(0)
#define BAR()    __builtin_amdgcn_s_barrier()
#define PRIO(p)  __builtin_amdgcn_s_setprio(p)

// LDS layout (144 KiB):
//   [0, 48K):    A-m0 ring, 3 slots of 16 KiB (slot = kt % 3)
//   [48K, 80K):  A-m1, 2 buffers of 16 KiB (buf = kt & 1)
//   [80K, 144K): B, 2 buffers of 32 KiB (buf = kt & 1)
// Unit mq rows: [wr0: global mq*64..+63][wr1: 128+mq*64..+63]. Rows 128 B;
// 8 chunks of 16 B at position p = chunk ^ (row&7) (XOR swizzle; linear dest +
// inverse-swizzled global source). All of tile t resident at tile-entry barrier.
__global__ __launch_bounds__(512, 1) void gemm_bias_lora(
    const __hip_bfloat16* __restrict__ Xb,   // [M, K]
    const __hip_bfloat16* __restrict__ Wb,   // [N, K]
    const float* __restrict__ bias,          // [N]
    const float* __restrict__ xa,            // [M, 8] pre-scaled & gated
    const float* __restrict__ loraB,         // [N, 8]
    float* __restrict__ out) {
    __shared__ char smem[147456];            // 144 KiB

    int tid = threadIdx.x;
    int bid = blockIdx.x;
    int swz = (bid & 7) * 128 + (bid >> 3);  // XCD-bijective, nwg=1024
    int n_tile = swz & 15;
    int m_tile = swz >> 4;
    int m_base = m_tile * BM, n_base = n_tile * BN;
    int wave = tid >> 6, lane = tid & 63;
    int wr = wave >> 2, wc = wave & 3;       // 2M x 4N waves, per-wave 128x64
    int l15 = lane & 15, lhi = lane >> 4;
    int l8 = lane >> 3;
    int cx = ((lane & 7) ^ l8) * 16;          // staging source chunk (inverse swizzle)
    int pswz0 = ((lhi)     ^ (l15 & 7)) * 16; // read chunk byte, ks=0
    int pswz1 = ((4 + lhi) ^ (l15 & 7)) * 16; // read chunk byte, ks=1
    int psA = wr ? pswz1 : pswz0;             // SIMD-pair skew (verified neutral)
    int psB = wr ? pswz0 : pswz1;

    f32x4 acc[8][4] = {};

    const char* Abase = (const char*)(Xb + (size_t)m_base * K_DIM);
    const char* Bbase = (const char*)(Wb + (size_t)n_base * K_DIM);

    auto stage_Au = [&](int kt, int mq, char* ubase) {
#pragma unroll
        for (int j = 0; j < 2; j++) {
            int rg = wave * 2 + j;
            int rl = rg * 8 + l8;
            int g = (rl < 64) ? (mq * 64 + rl) : (128 + mq * 64 + (rl - 64));
            gload_lds16(Abase + (size_t)g * (K_DIM * 2) + (size_t)kt * 128 + cx,
                        ubase + rg * 1024 + lane * 16);
        }
    };
    auto stage_B = [&](int kt, int h, int buf) {
        char* ub = smem + 81920 + buf * 32768 + h * 16384;
#pragma unroll
        for (int j = 0; j < 2; j++) {
            int rg = wave * 2 + j;
            int row = h * 128 + rg * 8 + l8;
            gload_lds16(Bbase + (size_t)row * (K_DIM * 2) + (size_t)kt * 128 + cx,
                        ub + rg * 1024 + lane * 16);
        }
    };

    // prologue: tile0 {A-m0 slot0, B buf0 h0/h1, A-m1 buf0} + A-m0(1) slot1
    stage_Au(0, 0, smem);
    stage_B(0, 0, 0); stage_B(0, 1, 0);
    stage_Au(0, 1, smem + 49152);
    stage_Au(1, 0, smem + 16384);
    VMCW(2);
    BAR();

    bf16x8 af0[4], af1[4], bf0[4], bf1[4];
    int s0 = 0;

    for (int t = 0; t < NT2; t++) {
        int cb = t & 1, nb = cb ^ 1;
        int s2 = s0 + 2; if (s2 >= 3) s2 -= 3;
        const char* aU0 = smem + s0 * 16384 + (wr * 64 + l15) * 128;
        const char* aU1 = smem + 49152 + cb * 16384 + (wr * 64 + l15) * 128;
        const char* bRb = smem + 81920 + cb * 32768 + (wc * 64 + l15) * 128;

        // ---- P0: reads af0(ksA), bf0(ksA) + ahead af1(ksA); stage B-h0(t+1) ----
#pragma unroll
        for (int mi = 0; mi < 4; mi++) af0[mi] = *(const bf16x8*)(aU0 + mi * 2048 + psA);
#pragma unroll
        for (int ni = 0; ni < 4; ni++) bf0[ni] = *(const bf16x8*)(bRb + ni * 2048 + psA);
#pragma unroll
        for (int mi = 0; mi < 4; mi++) af1[mi] = *(const bf16x8*)(aU1 + mi * 2048 + psA);
        if (t + 1 < NT2) stage_B(t + 1, 0, nb);
        LGKMW(4); SB0();
        PRIO(1);
#pragma unroll
        for (int mi = 0; mi < 4; mi++)
#pragma unroll
            for (int ni = 0; ni < 4; ni++)
                acc[mi][ni] = __builtin_amdgcn_mfma_f32_16x16x32_bf16(af0[mi], bf0[ni], acc[mi][ni], 0, 0, 0);
        PRIO(0);

        // ---- P1: ahead reads af0(ksB), bf1(ksB); stage B-h1(t+1), A-m1(t+1); MFMA af1xbf0 ----
#pragma unroll
        for (int mi = 0; mi < 4; mi++) af0[mi] = *(const bf16x8*)(aU0 + mi * 2048 + psB);
#pragma unroll
        for (int ni = 0; ni < 4; ni++) bf1[ni] = *(const bf16x8*)(bRb + ni * 2048 + psB);
        if (t + 1 < NT2) { stage_B(t + 1, 1, nb); stage_Au(t + 1, 1, smem + 49152 + nb * 16384); }
        LGKMW(8); SB0();
        PRIO(1);
#pragma unroll
        for (int mi = 0; mi < 4; mi++)
#pragma unroll
            for (int ni = 0; ni < 4; ni++)
                acc[4 + mi][ni] = __builtin_amdgcn_mfma_f32_16x16x32_bf16(af1[mi], bf0[ni], acc[4 + mi][ni], 0, 0, 0);
        PRIO(0);

        // ---- P2: ahead read af1(ksB); MFMA af0xbf1 ----
#pragma unroll
        for (int mi = 0; mi < 4; mi++) af1[mi] = *(const bf16x8*)(aU1 + mi * 2048 + psB);
        LGKMW(4); SB0();
        PRIO(1);
#pragma unroll
        for (int mi = 0; mi < 4; mi++)
#pragma unroll
            for (int ni = 0; ni < 4; ni++)
                acc[mi][ni] = __builtin_amdgcn_mfma_f32_16x16x32_bf16(af0[mi], bf1[ni], acc[mi][ni], 0, 0, 0);
        PRIO(0);

        // ---- P3: stage A-m0(t+2) -> ring slot s2; MFMA af1xbf1 ----
        if (t + 2 < NT2) stage_Au(t + 2, 0, smem + s2 * 16384);
        LGKMW(0); SB0();
        PRIO(1);
#pragma unroll
        for (int mi = 0; mi < 4; mi++)
#pragma unroll
            for (int ni = 0; ni < 4; ni++)
                acc[4 + mi][ni] = __builtin_amdgcn_mfma_f32_16x16x32_bf16(af1[mi], bf1[ni], acc[4 + mi][ni], 0, 0, 0);
        PRIO(0);
        if (t < NT2 - 2) { VMCW(2); } else { VMCW(0); }
        BAR();

        s0 = s0 + 1; if (s0 >= 3) s0 -= 3;
    }

    // epilogue: C/D layout col = lane&15, row = (lane>>4)*4 + reg; nt stores
    int wrow = m_base + wr * 128;
    int wcol = n_base + wc * 64;
    float bv[4];
    float4 lb0[4], lb1[4];
#pragma unroll
    for (int ni = 0; ni < 4; ni++) {
        int n = wcol + ni * 16 + l15;
        bv[ni] = bias[n];
        lb0[ni] = *(const float4*)(loraB + (size_t)n * 8);
        lb1[ni] = *(const float4*)(loraB + (size_t)n * 8 + 4);
    }
#pragma unroll
    for (int mi = 0; mi < 8; mi++) {
#pragma unroll
        for (int r = 0; r < 4; r++) {
            int m = wrow + mi * 16 + lhi * 4 + r;
            float4 xa0 = *(const float4*)(xa + (size_t)m * 8);
            float4 xa1 = *(const float4*)(xa + (size_t)m * 8 + 4);
#pragma unroll
            for (int ni = 0; ni < 4; ni++) {
                int n = wcol + ni * 16 + l15;
                float lora = xa0.x * lb0[ni].x + xa0.y * lb0[ni].y + xa0.z * lb0[ni].z + xa0.w * lb0[ni].w
                           + xa1.x * lb1[ni].x + xa1.y * lb1[ni].y + xa1.z * lb1[ni].z + xa1.w * lb1[ni].w;
                __builtin_nontemporal_store(acc[mi][ni][r] + bv[ni] + lora,
                                            &out[(size_t)m * N_DIM + n]);
            }
        }
    }
}

// ---------------- fallback (ws too small): correct but slow ----------------
__global__ void fallback_kernel(const float* __restrict__ x, const int* __restrict__ ids,
                                const float* __restrict__ W, const float* __restrict__ b,
                                const float* __restrict__ A, const float* __restrict__ B8,
                                float* __restrict__ out) {
    __shared__ float xs[K_DIM];
    __shared__ float xa_s[8];
    int row = blockIdx.y;
    int t = threadIdx.x;
    const float* xr = x + (size_t)row * K_DIM;
    for (int k = t; k < K_DIM; k += 256) xs[k] = xr[k];
    __syncthreads();
    if (t < 8) {
        float s = 0.f;
        for (int k = 0; k < K_DIM; k++) s += xs[k] * A[t * K_DIM + k];
        xa_s[t] = (ids[row] == 7) ? s * 2.0f : 0.0f;
    }
    __syncthreads();
    int col = blockIdx.x * 256 + t;
    const float* wr = W + (size_t)col * K_DIM;
    float acc = 0.f;
    for (int k = 0; k < K_DIM; k++) acc += xs[k] * wr[k];
    float lora = 0.f;
#pragma unroll
    for (int rr = 0; rr < 8; rr++) lora += xa_s[rr] * B8[col * 8 + rr];
    out[(size_t)row * N_DIM + col] = acc + b[col] + lora;
}

extern "C" void kernel_launch(void* const* d_in, const int* in_sizes, int n_in,
                              void* d_out, int out_size, void* d_ws, size_t ws_size,
                              hipStream_t stream) {
    const float* x   = (const float*)d_in[0];
    const int*   ids = (const int*)d_in[1];
    const float* W   = (const float*)d_in[2];
    const float* b   = (const float*)d_in[3];
    const float* lA  = (const float*)d_in[4];
    const float* lB  = (const float*)d_in[5];
    float* out = (float*)d_out;

    size_t wb_bytes = (size_t)N_DIM * K_DIM * 2;          // 32 MiB
    size_t xb_bytes = (size_t)M_DIM * K_DIM * 2;          // 128 MiB
    size_t xa_bytes = (size_t)M_DIM * 8 * 4;              // 0.5 MiB
    size_t ab_bytes = (size_t)8 * K_DIM * 2;              // 64 KiB

    if (ws_size >= wb_bytes + xb_bytes + xa_bytes + ab_bytes) {
        __hip_bfloat16* Wb  = (__hip_bfloat16*)d_ws;
        __hip_bfloat16* Xb  = (__hip_bfloat16*)((char*)d_ws + wb_bytes);
        float*          xav = (float*)((char*)d_ws + wb_bytes + xb_bytes);
        __hip_bfloat16* Abf = (__hip_bfloat16*)((char*)d_ws + wb_bytes + xb_bytes + xa_bytes);

        cvt_wa<<<1024 + 16, 256, 0, stream>>>(W, Wb, lA, Abf);
        cvt_x_xa<<<M_DIM / 8, 256, 0, stream>>>(x, ids, Abf, Xb, xav);
        gemm_bias_lora<<<(M_DIM / BM) * (N_DIM / BN), 512, 0, stream>>>(Xb, Wb, b, xav, lB, out);
    } else {
        fallback_kernel<<<dim3(N_DIM / 256, M_DIM), 256, 0, stream>>>(x, ids, W, b, lA, lB, out);
    }
}